// Round 19
// baseline (512.769 us; speedup 1.0000x reference)
//
#include <hip/hip_runtime.h>

typedef unsigned short u16;
typedef unsigned int u32;
typedef __attribute__((ext_vector_type(4))) float f32x4;
typedef __attribute__((ext_vector_type(16))) float f32x16;
typedef __attribute__((ext_vector_type(8))) short bf16x8;

// Problem sizes (fixed): B=2, S=2048, D=2048, NH=16, NKV=4, HD=128

__device__ __forceinline__ u16 f2b(float f) {
  u32 u = __builtin_bit_cast(u32, f);
  u = (u + 0x7fffu + ((u >> 16) & 1u)) >> 16;  // RNE
  return (u16)u;
}

__device__ __forceinline__ void gload_lds16(const void* g, void* l) {
  __builtin_amdgcn_global_load_lds((const __attribute__((address_space(1))) u32*)g,
                                   (__attribute__((address_space(3))) u32*)l, 16, 0, 0);
}

// ---- cross-half (lane <-> lane^32) exchange via v_permlane32_swap_b32 (VALU pipe) ----
#if __has_builtin(__builtin_amdgcn_permlane32_swap)
#define HAS_PLS 1
__device__ __forceinline__ void pls(u32 x, u32 y, u32& rx, u32& ry) {
  auto r = __builtin_amdgcn_permlane32_swap(x, y, false, false);
  rx = (u32)r[0];
  ry = (u32)r[1];
}
#endif

__device__ __forceinline__ float xhalf_max(float v) {
#ifdef HAS_PLS
  u32 a, b;
  pls(__builtin_bit_cast(u32, v), __builtin_bit_cast(u32, v), a, b);
  return fmaxf(__builtin_bit_cast(float, a), __builtin_bit_cast(float, b));
#else
  return fmaxf(v, __shfl_xor(v, 32));
#endif
}

__device__ __forceinline__ float xhalf_sum(float v) {
#ifdef HAS_PLS
  u32 a, b;
  pls(__builtin_bit_cast(u32, v), __builtin_bit_cast(u32, v), a, b);
  return __builtin_bit_cast(float, a) + __builtin_bit_cast(float, b);
#else
  return v + __shfl_xor(v, 32);
#endif
}

// P-fragment redistribution across lane halves
__device__ __forceinline__ void xexchange(int hi, u32 a0, u32 a1, u32 a2, u32 a3, u32* o) {
#ifdef HAS_PLS
  pls(a0, a2, o[0], o[2]);
  pls(a1, a3, o[1], o[3]);
#else
  u32 xa0 = (u32)__shfl_xor((int)a0, 32), xa1 = (u32)__shfl_xor((int)a1, 32);
  u32 xa2 = (u32)__shfl_xor((int)a2, 32), xa3 = (u32)__shfl_xor((int)a3, 32);
  o[0] = hi ? xa2 : a0;
  o[1] = hi ? xa3 : a1;
  o[2] = hi ? a2 : xa0;
  o[3] = hi ? a3 : xa1;
#endif
}

// truncating bf16 pair pack (P in [0,1]; <=2^-8 rel err, cheap: 3 ops)
__device__ __forceinline__ u32 pktrunc(float lo, float hif) {
  return (__builtin_bit_cast(u32, lo) >> 16) | (__builtin_bit_cast(u32, hif) & 0xffff0000u);
}

// ---------------- fused fp32 -> bf16 conversion: X + Wq + Wk + Wv in one launch ----------------
// dst layout (contiguous): [Xb 8388608 | Wqb 4194304 | Wkb 1048576 | Wvb 1048576]
__global__ void cvt_all(const float* __restrict__ X, const float* __restrict__ Wq,
                        const float* __restrict__ Wk, const float* __restrict__ Wv,
                        u16* __restrict__ dst) {
  const int total = 14680064;
  int stride = gridDim.x * blockDim.x * 4;
  for (int idx = (blockIdx.x * blockDim.x + threadIdx.x) * 4; idx < total; idx += stride) {
    const float* src;
    int off;
    if (idx < 8388608) { src = X; off = idx; }
    else if (idx < 12582912) { src = Wq; off = idx - 8388608; }
    else if (idx < 13631488) { src = Wk; off = idx - 12582912; }
    else { src = Wv; off = idx - 13631488; }
    float4 v = *(const float4*)(src + off);
    ushort4 o;
    o.x = f2b(v.x); o.y = f2b(v.y); o.z = f2b(v.z); o.w = f2b(v.w);
    *(ushort4*)(dst + idx) = o;
  }
}

// ---------------- 256x256 8-phase GEMM (QKV): C[M,N] = A[M,K] * B[N,K]^T ----------------
// grid (16,16): blockIdx.x < 12 -> GEMM N-tile; blockIdx.x >= 12 -> 64 aux blocks convert
// Wo fp32->bf16 (fills the 64 CUs the 192-block GEMM leaves idle; removes cvt from the
// serial timeline). 512 threads, BK=64, 128 KB LDS dbuf, T2 XOR-swizzle both-sides,
// counted vmcnt (4@q0 / 6@q2), raw s_barrier, T5 setprio.
// OUT_MODE 3 = fused QKV routing (Q row-major, K/V fragment order via LDS-staged epilogue).
template<int OUT_MODE>
__global__ __launch_bounds__(512) void gemm256(const u16* __restrict__ A, const u16* __restrict__ B,
                                               void* __restrict__ Cout, int M, int N, int Kd,
                                               u16* __restrict__ Kout, u16* __restrict__ Vout,
                                               const float* __restrict__ WoSrc,
                                               u16* __restrict__ WoDst) {
  __shared__ u16 smem[65536];  // 128 KB: [slot0: A 16384 | B 16384][slot1: ...]
  const int tid = threadIdx.x;

  if constexpr (OUT_MODE == 3) {
    if (blockIdx.x >= 12) {  // aux: Wo conversion (4194304 elems over 64 blocks)
      const int id = ((int)blockIdx.x - 12) * (int)gridDim.y + (int)blockIdx.y;
      const int base = id * 65536;
#pragma unroll 4
      for (int j = tid * 4; j < 65536; j += 2048) {
        float4 v = *(const float4*)(WoSrc + base + j);
        ushort4 o;
        o.x = f2b(v.x); o.y = f2b(v.y); o.z = f2b(v.z); o.w = f2b(v.w);
        *(ushort4*)(WoDst + base + j) = o;
      }
      return;
    }
  }

  const int l = tid & 63, w = tid >> 6;
  const int c = l & 15, g = l >> 4;
  const int wr = w >> 2, wc = w & 3;
  const int tm = blockIdx.y * 256, tn = blockIdx.x * 256;

  const int lr = tid >> 3;           // row within round
  const int lcol = (tid & 7) * 8;    // dest u16 col
  const int scol = lcol ^ (((lr >> 1) & 3) << 4);  // inverse-swizzled source col
  const int swc = ((c >> 1) & 3) << 4;             // read-side swizzle (row bits = c)

#define BARX() do { __builtin_amdgcn_s_barrier(); asm volatile("" ::: "memory"); } while (0)
#define STG(SRC, GROW0, LDS0) \
  gload_lds16((SRC) + (size_t)((GROW0) + lr) * Kd + k0n + scol, (LDS0) + lr * 64 + lcol)

  f32x4 acc[8][4] = {};

  {
    const int k0n = 0;
    u16* sAn = smem;
    u16* sBn = smem + 16384;
    STG(B, tn + 0, sBn); STG(B, tn + 64, sBn + 64 * 64);
    STG(B, tn + 128, sBn + 128 * 64); STG(B, tn + 192, sBn + 192 * 64);
    STG(A, tm + 0, sAn); STG(A, tm + 128, sAn + 128 * 64);
    STG(A, tm + 64, sAn + 64 * 64); STG(A, tm + 192, sAn + 192 * 64);
  }

  const int nt = Kd >> 6;
  for (int t = 0; t < nt; ++t) {
    const int slot = t & 1;
    u16* sAc = smem + slot * 32768;
    u16* sBc = sAc + 16384;
    u16* sAn = smem + (slot ^ 1) * 32768;
    u16* sBn = sAn + 16384;
    const int k0n = (t + 1) << 6;
    const bool st = (t + 1) < nt;

    bf16x8 bfr[4][2], af[2][2];

#define APH(q)                                                                  \
  do {                                                                          \
    _Pragma("unroll") for (int m2 = 0; m2 < 2; ++m2)                            \
    _Pragma("unroll") for (int kk = 0; kk < 2; ++kk)                            \
        af[m2][kk] = *(const bf16x8*)(sAc + (wr * 128 + (q) * 32 + m2 * 16 + c) * 64 + \
                                      ((kk * 32 + g * 8) ^ swc));               \
    __builtin_amdgcn_s_setprio(1);                                              \
    _Pragma("unroll") for (int m2 = 0; m2 < 2; ++m2)                            \
    _Pragma("unroll") for (int n = 0; n < 4; ++n)                               \
    _Pragma("unroll") for (int kk = 0; kk < 2; ++kk)                            \
        acc[(q) * 2 + m2][n] = __builtin_amdgcn_mfma_f32_16x16x32_bf16(         \
            af[m2][kk], bfr[n][kk], acc[(q) * 2 + m2][n], 0, 0, 0);             \
    __builtin_amdgcn_s_setprio(0);                                              \
  } while (0)

    // ---- q0 ----
    BARX();
    if (st) { STG(B, tn + 0, sBn); STG(B, tn + 64, sBn + 64 * 64); }
    if (st) asm volatile("s_waitcnt vmcnt(4)" ::: "memory");
    else    asm volatile("s_waitcnt vmcnt(2)" ::: "memory");
    BARX();
#pragma unroll
    for (int n = 0; n < 4; ++n)
#pragma unroll
      for (int kk = 0; kk < 2; ++kk)
        bfr[n][kk] = *(const bf16x8*)(sBc + (wc * 64 + n * 16 + c) * 64 +
                                      ((kk * 32 + g * 8) ^ swc));
    APH(0);
    // ---- q1 ----
    if (st) { STG(B, tn + 128, sBn + 128 * 64); STG(B, tn + 192, sBn + 192 * 64); }
    APH(1);
    // ---- q2 ----
    if (st) { STG(A, tm + 0, sAn); STG(A, tm + 128, sAn + 128 * 64); }
    if (st) asm volatile("s_waitcnt vmcnt(6)" ::: "memory");
    else    asm volatile("s_waitcnt vmcnt(0)" ::: "memory");
    BARX();
    APH(2);
    // ---- q3 ----
    if (st) { STG(A, tm + 64, sAn + 64 * 64); STG(A, tm + 192, sAn + 192 * 64); }
    APH(3);
#undef APH
  }

  if constexpr (OUT_MODE == 3) {
    if (tn >= 2048) {
      // ---- K/V fragment-order epilogue: scatter to 128KB LDS, then 16x8KB coalesced copy
      const bool isK = tn < 2560;
      BARX();
#pragma unroll
      for (int mi = 0; mi < 8; ++mi)
#pragma unroll
        for (int n = 0; n < 4; ++n)
#pragma unroll
          for (int i = 0; i < 4; ++i) {
            int s = wr * 128 + (mi >> 1) * 32 + (mi & 1) * 16 + g * 4 + i;  // kv row
            int e = wc * 64 + n * 16 + c;                                    // k or d col
            int chunk = (e >> 7) * 8 + (s >> 5);
            int off;
            if (isK) {
              int k = e & 127;
              off = chunk * 4096 + (k >> 4) * 512 + ((k >> 3) & 1) * 256 + (s & 31) * 8 + (k & 7);
            } else {
              int d = e & 127;
              off = chunk * 4096 + (((s >> 4) & 1) * 4 + (d >> 5)) * 512 + ((s >> 3) & 1) * 256 +
                    (d & 31) * 8 + (s & 7);
            }
            smem[off] = f2b(acc[mi][n][i]);
          }
      BARX();
      const int kvh_base = (tn - (isK ? 2048 : 2560)) >> 7;
      const int bb = tm >> 11;
      const int kvt0 = (tm & 2047) >> 5;
      u16* Out = isK ? Kout : Vout;
#pragma unroll
      for (int ch = 0; ch < 16; ++ch) {
        u16* dst = Out + (size_t)((bb * 4 + kvh_base + (ch >> 3)) * 64 + kvt0 + (ch & 7)) * 4096;
        *(bf16x8*)(dst + tid * 8) = *(const bf16x8*)(smem + ch * 4096 + tid * 8);
      }
      return;
    }
    // Q tiles: bf16 row-major, ld 2048
#pragma unroll
    for (int mi = 0; mi < 8; ++mi)
#pragma unroll
      for (int n = 0; n < 4; ++n)
#pragma unroll
        for (int i = 0; i < 4; ++i) {
          int row = tm + wr * 128 + (mi >> 1) * 32 + (mi & 1) * 16 + g * 4 + i;
          int col = tn + wc * 64 + n * 16 + c;
          ((u16*)Cout)[(size_t)row * 2048 + col] = f2b(acc[mi][n][i]);
        }
    return;
  }

  // OUT_MODE 2: fp32 row-major
#pragma unroll
  for (int mi = 0; mi < 8; ++mi)
#pragma unroll
    for (int n = 0; n < 4; ++n)
#pragma unroll
      for (int i = 0; i < 4; ++i) {
        int row = tm + wr * 128 + (mi >> 1) * 32 + (mi & 1) * 16 + g * 4 + i;
        int col = tn + wc * 64 + n * 16 + c;
        ((float*)Cout)[(size_t)row * N + col] = acc[mi][n][i];
      }
#undef STG
#undef BARX
}

// ---------------- 256x128 8-phase GEMM (O-proj): C[4096,2048] fp32 = A * B^T ----------------
// 96 KB LDS, grid (16,16)=256 blocks = 100% CU fill. Waits vmcnt(4)@q0, vmcnt(6)@q2.
__global__ __launch_bounds__(512) void gemm_op(const u16* __restrict__ A, const u16* __restrict__ B,
                                               float* __restrict__ Cout, int Kd) {
  __shared__ u16 smem[49152];  // 96 KB: [slot: A 16384 | B 8192] x 2
  const int tid = threadIdx.x;
  const int l = tid & 63, w = tid >> 6;
  const int c = l & 15, g = l >> 4;
  const int wr = w >> 2, wc = w & 3;
  const int tm = blockIdx.y * 256, tn = blockIdx.x * 128;

  const int lr = tid >> 3;
  const int lcol = (tid & 7) * 8;
  const int scol = lcol ^ (((lr >> 1) & 3) << 4);
  const int swc = ((c >> 1) & 3) << 4;

#define BARX() do { __builtin_amdgcn_s_barrier(); asm volatile("" ::: "memory"); } while (0)
#define STG(SRC, GROW0, LDS0) \
  gload_lds16((SRC) + (size_t)((GROW0) + lr) * Kd + k0n + scol, (LDS0) + lr * 64 + lcol)

  f32x4 acc[8][2] = {};

  {
    const int k0n = 0;
    u16* sAn = smem;
    u16* sBn = smem + 16384;
    STG(B, tn + 0, sBn); STG(B, tn + 64, sBn + 64 * 64);
    STG(A, tm + 0, sAn); STG(A, tm + 128, sAn + 128 * 64);
    STG(A, tm + 64, sAn + 64 * 64); STG(A, tm + 192, sAn + 192 * 64);
  }

  const int nt = Kd >> 6;
  for (int t = 0; t < nt; ++t) {
    const int slot = t & 1;
    u16* sAc = smem + slot * 24576;
    u16* sBc = sAc + 16384;
    u16* sAn = smem + (slot ^ 1) * 24576;
    u16* sBn = sAn + 16384;
    const int k0n = (t + 1) << 6;
    const bool st = (t + 1) < nt;

    bf16x8 bfr[2][2], af[2][2];

#define APH(q)                                                                  \
  do {                                                                          \
    _Pragma("unroll") for (int m2 = 0; m2 < 2; ++m2)                            \
    _Pragma("unroll") for (int kk = 0; kk < 2; ++kk)                            \
        af[m2][kk] = *(const bf16x8*)(sAc + (wr * 128 + (q) * 32 + m2 * 16 + c) * 64 + \
                                      ((kk * 32 + g * 8) ^ swc));               \
    __builtin_amdgcn_s_setprio(1);                                              \
    _Pragma("unroll") for (int m2 = 0; m2 < 2; ++m2)                            \
    _Pragma("unroll") for (int n = 0; n < 2; ++n)                               \
    _Pragma("unroll") for (int kk = 0; kk < 2; ++kk)                            \
        acc[(q) * 2 + m2][n] = __builtin_amdgcn_mfma_f32_16x16x32_bf16(         \
            af[m2][kk], bfr[n][kk], acc[(q) * 2 + m2][n], 0, 0, 0);             \
    __builtin_amdgcn_s_setprio(0);                                              \
  } while (0)

    // ---- q0 ----
    BARX();
    if (st) { STG(B, tn + 0, sBn); STG(B, tn + 64, sBn + 64 * 64); }
    if (st) asm volatile("s_waitcnt vmcnt(4)" ::: "memory");
    else    asm volatile("s_waitcnt vmcnt(2)" ::: "memory");
    BARX();
#pragma unroll
    for (int n = 0; n < 2; ++n)
#pragma unroll
      for (int kk = 0; kk < 2; ++kk)
        bfr[n][kk] = *(const bf16x8*)(sBc + (wc * 32 + n * 16 + c) * 64 +
                                      ((kk * 32 + g * 8) ^ swc));
    APH(0);
    // ---- q1 ----
    if (st) { STG(A, tm + 0, sAn); STG(A, tm + 128, sAn + 128 * 64); }
    APH(1);
    // ---- q2 ----
    if (st) { STG(A, tm + 64, sAn + 64 * 64); STG(A, tm + 192, sAn + 192 * 64); }
    if (st) asm volatile("s_waitcnt vmcnt(6)" ::: "memory");
    else    asm volatile("s_waitcnt vmcnt(0)" ::: "memory");
    BARX();
    APH(2);
    // ---- q3 ----
    APH(3);
#undef APH
  }

  // fp32 row-major epilogue (N = 2048)
#pragma unroll
  for (int mi = 0; mi < 8; ++mi)
#pragma unroll
    for (int n = 0; n < 2; ++n)
#pragma unroll
      for (int i = 0; i < 4; ++i) {
        int row = tm + wr * 128 + (mi >> 1) * 32 + (mi & 1) * 16 + g * 4 + i;
        int col = tn + wc * 32 + n * 16 + c;
        Cout[(size_t)row * 2048 + col] = acc[mi][n][i];
      }
#undef STG
#undef BARX
}

// ---------------- causal GQA flash attention: 32x32 swapped-operand, pipelined ----
// grid (1024), block 256 (4 waves). XCD-affinity decode; 2 phases/block (x, 63-x);
// wave w takes kv-tiles (w+4i)*32; 2-stage merge. K/V MFMA-fragment-ordered.
// T15-ANALOG PIPELINE (r19): tile i+1's QK MFMAs are issued BEFORE tile i's softmax.
// MFMA and VALU are separate pipes — after the 8 independent QK MFMAs issue, the wave
// immediately issues softmax VALU for the PREVIOUS sacc (no register dep), so the matrix
// pipe and VALU overlap within the wave. K prefetch is 2-deep; sacc is ping-ponged.
// NOTE: min-waves arg MUST be 2 — (256,4) caps VGPR at 64 and spills (round 8: 5x regression).
__global__ __launch_bounds__(256, 2) void attn_fwd(const u16* __restrict__ Q, const u16* __restrict__ Kf,
                                                   const u16* __restrict__ Vf, u16* __restrict__ AO) {
  const int l = threadIdx.x & 63, w = threadIdx.x >> 6;
  const int ql = l & 31, hi = l >> 5;
  const int id = (int)blockIdx.x;
  const int xcd = id & 7, slot = id >> 3;
  const int bh = xcd + 8 * (slot >> 5);
  const int x = slot & 31;
  const int b = bh >> 4, h = bh & 15;
  const int kvh = h >> 2;

  __shared__ float4 mO[2][16][64];
  __shared__ float mML[2][2][64];

  const float sm = 0.08838834764831845f * 1.4426950408889634f;  // 1/sqrt(128) * log2(e)

  const u16* Kfb = Kf + (size_t)(b * 4 + kvh) * 64 * 4096 + l * 8;
  const u16* Vfb = Vf + (size_t)(b * 4 + kvh) * 64 * 4096 + l * 8;

#define LOADK(KF, KV0)                                                        \
  do {                                                                        \
    const u16* kb_ = Kfb + (size_t)((KV0) >> 5) * 4096;                       \
    _Pragma("unroll") for (int ck = 0; ck < 8; ++ck)                          \
        KF[ck] = *(const bf16x8*)(kb_ + ck * 512);                            \
  } while (0)

#define LOADV(VT, KV0)                                                        \
  do {                                                                        \
    const u16* vb_ = Vfb + (size_t)((KV0) >> 5) * 4096;                       \
    _Pragma("unroll") for (int ks = 0; ks < 2; ++ks)                          \
    _Pragma("unroll") for (int db = 0; db < 4; ++db)                          \
        VT[ks][db] = *(const bf16x8*)(vb_ + (ks * 4 + db) * 512);             \
  } while (0)

// QK only: SACC = K^T Q for one 32x32 tile (8 MFMA, pure matrix-pipe)
#define QKC(SACC, KF)                                                         \
  do {                                                                        \
    SACC = (f32x16){};                                                        \
    __builtin_amdgcn_s_setprio(1);                                            \
    _Pragma("unroll") for (int ck = 0; ck < 8; ++ck)                          \
        SACC = __builtin_amdgcn_mfma_f32_32x32x16_bf16(KF[ck], qf[ck], SACC, 0, 0, 0); \
    __builtin_amdgcn_s_setprio(0);                                            \
  } while (0)

// softmax + PV for an already-computed SACC (VALU + 8 MFMA)
#define SMPV(SACC, VT, KV0)                                                   \
  do {                                                                        \
    if ((KV0) == q0) { /* diagonal: mask kv > q */                            \
      _Pragma("unroll") for (int r = 0; r < 16; ++r) {                        \
        int crow = (r & 3) + 8 * (r >> 2) + 4 * hi;                           \
        if (crow > ql) SACC[r] = -1e30f;                                      \
      }                                                                       \
    }                                                                         \
    float t0 = fmaxf(SACC[0], SACC[1]), t1 = fmaxf(SACC[2], SACC[3]);         \
    float t2 = fmaxf(SACC[4], SACC[5]), t3 = fmaxf(SACC[6], SACC[7]);         \
    float t4 = fmaxf(SACC[8], SACC[9]), t5 = fmaxf(SACC[10], SACC[11]);       \
    float t6 = fmaxf(SACC[12], SACC[13]), t7 = fmaxf(SACC[14], SACC[15]);     \
    float mx = fmaxf(fmaxf(fmaxf(t0, t1), fmaxf(t2, t3)),                     \
                     fmaxf(fmaxf(t4, t5), fmaxf(t6, t7)));                    \
    mx = xhalf_max(mx);                                                       \
    float p[16];                                                              \
    _Pragma("unroll") for (int r = 0; r < 16; ++r)                            \
        p[r] = exp2f((SACC[r] - mrow) * sm);                                  \
    if (!__all((mx - mrow) * sm <= 8.0f)) { /* T13 defer-max */               \
      float mnew = fmaxf(mrow, mx);                                           \
      float rs = exp2f((mrow - mnew) * sm);                                   \
      mrow = mnew;                                                            \
      lrow *= rs;                                                             \
      _Pragma("unroll") for (int db = 0; db < 4; ++db)                        \
      _Pragma("unroll") for (int r = 0; r < 16; ++r) acc[db][r] *= rs;        \
      _Pragma("unroll") for (int r = 0; r < 16; ++r)                          \
          p[r] = exp2f((SACC[r] - mrow) * sm);                                \
    }                                                                         \
    float s0 = p[0] + p[1], s1 = p[2] + p[3], s2 = p[4] + p[5], s3 = p[6] + p[7]; \
    float s4 = p[8] + p[9], s5 = p[10] + p[11], s6 = p[12] + p[13], s7 = p[14] + p[15]; \
    float psum = ((s0 + s1) + (s2 + s3)) + ((s4 + s5) + (s6 + s7));           \
    lrow += xhalf_sum(psum);                                                  \
    u32 a0 = pktrunc(p[0], p[1]), a1 = pktrunc(p[2], p[3]);                   \
    u32 a2 = pktrunc(p[4], p[5]), a3 = pktrunc(p[6], p[7]);                   \
    u32 b0 = pktrunc(p[8], p[9]), b1 = pktrunc(p[10], p[11]);                 \
    u32 b2 = pktrunc(p[12], p[13]), b3 = pktrunc(p[14], p[15]);               \
    union { bf16x8 v; u32 u[4]; } pa0, pa1;                                   \
    xexchange(hi, a0, a1, a2, a3, pa0.u);                                     \
    xexchange(hi, b0, b1, b2, b3, pa1.u);                                     \
    __builtin_amdgcn_s_setprio(1);                                            \
    _Pragma("unroll") for (int db = 0; db < 4; ++db) {                        \
      acc[db] = __builtin_amdgcn_mfma_f32_32x32x16_bf16(VT[0][db], pa0.v, acc[db], 0, 0, 0); \
      acc[db] = __builtin_amdgcn_mfma_f32_32x32x16_bf16(VT[1][db], pa1.v, acc[db], 0, 0, 0); \
    }                                                                         \
    __builtin_amdgcn_s_setprio(0);                                            \
  } while (0)

#define PUBLISH(SLOT)                                                         \
  do {                                                                        \
    _Pragma("unroll") for (int db = 0; db < 4; ++db)                          \
    _Pragma("unroll") for (int rq = 0; rq < 4; ++rq) {                        \
      float4 v;                                                               \
      v.x = acc[db][rq * 4 + 0];                                              \
      v.y = acc[db][rq * 4 + 1];                                              \
      v.z = acc[db][rq * 4 + 2];                                              \
      v.w = acc[db][rq * 4 + 3];                                              \
      mO[SLOT][db * 4 + rq][l] = v;                                           \
    }                                                                         \
    mML[SLOT][0][l] = mrow;                                                   \
    mML[SLOT][1][l] = lrow;                                                   \
  } while (0)

#define MERGE(SLOT)                                                           \
  do {                                                                        \
    float m1 = mML[SLOT][0][l], l1 = mML[SLOT][1][l];                         \
    float mnew = fmaxf(mrow, m1);                                             \
    float f0 = exp2f((mrow - mnew) * sm);                                     \
    float f1 = exp2f((m1 - mnew) * sm);                                       \
    mrow = mnew;                                                              \
    lrow = lrow * f0 + l1 * f1;                                               \
    _Pragma("unroll") for (int db = 0; db < 4; ++db)                          \
    _Pragma("unroll") for (int rq = 0; rq < 4; ++rq) {                        \
      float4 o1 = mO[SLOT][db * 4 + rq][l];                                   \
      acc[db][rq * 4 + 0] = acc[db][rq * 4 + 0] * f0 + o1.x * f1;             \
      acc[db][rq * 4 + 1] = acc[db][rq * 4 + 1] * f0 + o1.y * f1;             \
      acc[db][rq * 4 + 2] = acc[db][rq * 4 + 2] * f0 + o1.z * f1;             \
      acc[db][rq * 4 + 3] = acc[db][rq * 4 + 3] * f0 + o1.w * f1;             \
    }                                                                         \
  } while (0)

  for (int phase = 0; phase < 2; ++phase) {
    const int t = phase ? (63 - x) : x;
    const int q0 = t * 32;

    bf16x8 qf[8];
    {
      const u16* qb = Q + ((size_t)(b * 2048 + q0 + ql)) * 2048 + h * 128 + hi * 8;
#pragma unroll
      for (int ck = 0; ck < 8; ++ck) qf[ck] = *(const bf16x8*)(qb + ck * 16);
    }

    f32x16 acc[4] = {};
    float mrow = -1e30f, lrow = 0.f;

    bf16x8 kfa[8], kfb[8];
    bf16x8 vt[2][4];
    f32x16 sacc_a, sacc_b;

    int kv0 = w * 32;
    if (kv0 <= q0) {
      LOADK(kfa, kv0);
      bool more1 = kv0 + 128 <= q0;
      if (more1) LOADK(kfb, kv0 + 128);
      QKC(sacc_a, kfa);                       // tile 0 QK (prologue)
      while (true) {
        // cur = a
        LOADV(vt, kv0);
        {
          bool more2 = kv0 + 256 <= q0;
          if (more2) LOADK(kfa, kv0 + 256);   // 2-ahead K into freed buffer
          if (more1) QKC(sacc_b, kfb);        // next tile QK — overlaps SMPV below
          SMPV(sacc_a, vt, kv0);
          if (!more1) break;
          kv0 += 128;
          more1 = more2;
        }
        // cur = b
        LOADV(vt, kv0);
        {
          bool more2 = kv0 + 256 <= q0;
          if (more2) LOADK(kfb, kv0 + 256);
          if (more1) QKC(sacc_a, kfa);
          SMPV(sacc_b, vt, kv0);
          if (!more1) break;
          kv0 += 128;
          more1 = more2;
        }
      }
    }

    if (w >= 2) PUBLISH(w - 2);
    __syncthreads();
    if (w < 2) MERGE(w);
    __syncthreads();
    if (w == 1) PUBLISH(0);
    __syncthreads();
    if (w == 0) {
      MERGE(0);
      float inv = 1.0f / lrow;
      u16* ob = AO + (size_t)(b * 2048 + q0 + ql) * 2048 + h * 128 + hi * 4;
#pragma unroll
      for (int db = 0; db < 4; ++db)
#pragma unroll
        for (int rq = 0; rq < 4; ++rq) {
          ushort4 o;
          o.x = f2b(acc[db][rq * 4 + 0] * inv);
          o.y = f2b(acc[db][rq * 4 + 1] * inv);
          o.z = f2b(acc[db][rq * 4 + 2] * inv);
          o.w = f2b(acc[db][rq * 4 + 3] * inv);
          *(ushort4*)(ob + db * 32 + rq * 8) = o;
        }
    }
    __syncthreads();  // slot reuse guard before next phase's PUBLISH
  }
#undef LOADK
#undef LOADV
#undef QKC
#undef SMPV
#undef PUBLISH
#undef MERGE
}

// ---------------- host ----------------
extern "C" void kernel_launch(void* const* d_in, const int* in_sizes, int n_in,
                              void* d_out, int out_size, void* d_ws, size_t ws_size,
                              hipStream_t stream) {
  const float* X = (const float*)d_in[0];
  const float* Wq = (const float*)d_in[1];
  const float* Wk = (const float*)d_in[2];
  const float* Wv = (const float*)d_in[3];
  const float* Wo = (const float*)d_in[4];

  u16* ws = (u16*)d_ws;
  const size_t nX = 8388608;   // 2*2048*2048
  const size_t nWq = 4194304;  // 2048*2048
  const size_t nWk = 1048576;  // 512*2048
  u16* Xb = ws;
  u16* Wqb = Xb + nX;          // [Wq|Wk|Wv] contiguous = fused 3072x2048 weight
  u16* Wkb = Wqb + nWq;
  u16* Wvb = Wkb + nWk;
  u16* Wob = Wvb + nWk;
  u16* Qb = Wob + nWq;
  u16* Kfb = Qb + nX;          // K in fragment order (2M u16)
  u16* Vfb = Kfb + 2097152;    // V in fragment order (2M u16)
  u16* AOb = Vfb + 2097152;
  if (ws_size < (size_t)(39845888) * 2) return;

  // fused fp32->bf16: X + Wq + Wk + Wv (Wo converted by gemm256's 64 aux blocks)
  cvt_all<<<2048, 256, 0, stream>>>(X, Wq, Wk, Wv, Xb);

  // fused QKV projection (256^2 8-phase) + Wo conversion on spare blocks
  gemm256<3><<<dim3(16, 16), 512, 0, stream>>>(Xb, Wqb, Qb, 4096, 3072, 2048, Kfb, Vfb,
                                               Wo, Wob);

  attn_fwd<<<dim3(1024), 256, 0, stream>>>(Qb, Kfb, Vfb, AOb);

  // output projection (256x128 8-phase, 256 blocks = full chip) -> fp32 d_out
  gemm_op<<<dim3(16, 16), 512, 0, stream>>>(AOb, Wob, (float*)d_out, 2048);
}

// Round 20
// 190.352 us; speedup vs baseline: 2.6938x; 2.6938x over previous
//
#include <hip/hip_runtime.h>

typedef unsigned short u16;
typedef unsigned int u32;
typedef __attribute__((ext_vector_type(4))) float f32x4;
typedef __attribute__((ext_vector_type(16))) float f32x16;
typedef __attribute__((ext_vector_type(8))) short bf16x8;

// Problem sizes (fixed): B=2, S=2048, D=2048, NH=16, NKV=4, HD=128

__device__ __forceinline__ u16 f2b(float f) {
  u32 u = __builtin_bit_cast(u32, f);
  u = (u + 0x7fffu + ((u >> 16) & 1u)) >> 16;  // RNE
  return (u16)u;
}

__device__ __forceinline__ void gload_lds16(const void* g, void* l) {
  __builtin_amdgcn_global_load_lds((const __attribute__((address_space(1))) u32*)g,
                                   (__attribute__((address_space(3))) u32*)l, 16, 0, 0);
}

// ---- cross-half (lane <-> lane^32) exchange via v_permlane32_swap_b32 (VALU pipe) ----
#if __has_builtin(__builtin_amdgcn_permlane32_swap)
#define HAS_PLS 1
__device__ __forceinline__ void pls(u32 x, u32 y, u32& rx, u32& ry) {
  auto r = __builtin_amdgcn_permlane32_swap(x, y, false, false);
  rx = (u32)r[0];
  ry = (u32)r[1];
}
#endif

__device__ __forceinline__ float xhalf_max(float v) {
#ifdef HAS_PLS
  u32 a, b;
  pls(__builtin_bit_cast(u32, v), __builtin_bit_cast(u32, v), a, b);
  return fmaxf(__builtin_bit_cast(float, a), __builtin_bit_cast(float, b));
#else
  return fmaxf(v, __shfl_xor(v, 32));
#endif
}

__device__ __forceinline__ float xhalf_sum(float v) {
#ifdef HAS_PLS
  u32 a, b;
  pls(__builtin_bit_cast(u32, v), __builtin_bit_cast(u32, v), a, b);
  return __builtin_bit_cast(float, a) + __builtin_bit_cast(float, b);
#else
  return v + __shfl_xor(v, 32);
#endif
}

// P-fragment redistribution across lane halves
__device__ __forceinline__ void xexchange(int hi, u32 a0, u32 a1, u32 a2, u32 a3, u32* o) {
#ifdef HAS_PLS
  pls(a0, a2, o[0], o[2]);
  pls(a1, a3, o[1], o[3]);
#else
  u32 xa0 = (u32)__shfl_xor((int)a0, 32), xa1 = (u32)__shfl_xor((int)a1, 32);
  u32 xa2 = (u32)__shfl_xor((int)a2, 32), xa3 = (u32)__shfl_xor((int)a3, 32);
  o[0] = hi ? xa2 : a0;
  o[1] = hi ? xa3 : a1;
  o[2] = hi ? a2 : xa0;
  o[3] = hi ? a3 : xa1;
#endif
}

// truncating bf16 pair pack (P in [0,1]; <=2^-8 rel err, cheap: 3 ops)
__device__ __forceinline__ u32 pktrunc(float lo, float hif) {
  return (__builtin_bit_cast(u32, lo) >> 16) | (__builtin_bit_cast(u32, hif) & 0xffff0000u);
}

// ---------------- fused fp32 -> bf16 conversion: X + Wq + Wk + Wv in one launch ----------------
// dst layout (contiguous): [Xb 8388608 | Wqb 4194304 | Wkb 1048576 | Wvb 1048576]
__global__ void cvt_all(const float* __restrict__ X, const float* __restrict__ Wq,
                        const float* __restrict__ Wk, const float* __restrict__ Wv,
                        u16* __restrict__ dst) {
  const int total = 14680064;
  int stride = gridDim.x * blockDim.x * 4;
  for (int idx = (blockIdx.x * blockDim.x + threadIdx.x) * 4; idx < total; idx += stride) {
    const float* src;
    int off;
    if (idx < 8388608) { src = X; off = idx; }
    else if (idx < 12582912) { src = Wq; off = idx - 8388608; }
    else if (idx < 13631488) { src = Wk; off = idx - 12582912; }
    else { src = Wv; off = idx - 13631488; }
    float4 v = *(const float4*)(src + off);
    ushort4 o;
    o.x = f2b(v.x); o.y = f2b(v.y); o.z = f2b(v.z); o.w = f2b(v.w);
    *(ushort4*)(dst + idx) = o;
  }
}

// ---------------- 256x256 8-phase GEMM (QKV): C[M,N] = A[M,K] * B[N,K]^T ----------------
// grid (16,16): blockIdx.x < 12 -> GEMM N-tile; blockIdx.x >= 12 -> 64 aux blocks convert
// Wo fp32->bf16 (fills the 64 CUs the 192-block GEMM leaves idle). 512 threads, BK=64,
// 128 KB LDS dbuf, T2 XOR-swizzle both-sides, counted vmcnt (4@q0 / 6@q2), raw s_barrier,
// T5 setprio. OUT_MODE 3 = fused QKV routing (Q row-major, K/V fragment order).
template<int OUT_MODE>
__global__ __launch_bounds__(512) void gemm256(const u16* __restrict__ A, const u16* __restrict__ B,
                                               void* __restrict__ Cout, int M, int N, int Kd,
                                               u16* __restrict__ Kout, u16* __restrict__ Vout,
                                               const float* __restrict__ WoSrc,
                                               u16* __restrict__ WoDst) {
  __shared__ u16 smem[65536];  // 128 KB: [slot0: A 16384 | B 16384][slot1: ...]
  const int tid = threadIdx.x;

  if constexpr (OUT_MODE == 3) {
    if (blockIdx.x >= 12) {  // aux: Wo conversion (4194304 elems over 64 blocks)
      const int id = ((int)blockIdx.x - 12) * (int)gridDim.y + (int)blockIdx.y;
      const int base = id * 65536;
#pragma unroll 4
      for (int j = tid * 4; j < 65536; j += 2048) {
        float4 v = *(const float4*)(WoSrc + base + j);
        ushort4 o;
        o.x = f2b(v.x); o.y = f2b(v.y); o.z = f2b(v.z); o.w = f2b(v.w);
        *(ushort4*)(WoDst + base + j) = o;
      }
      return;
    }
  }

  const int l = tid & 63, w = tid >> 6;
  const int c = l & 15, g = l >> 4;
  const int wr = w >> 2, wc = w & 3;
  const int tm = blockIdx.y * 256, tn = blockIdx.x * 256;

  const int lr = tid >> 3;           // row within round
  const int lcol = (tid & 7) * 8;    // dest u16 col
  const int scol = lcol ^ (((lr >> 1) & 3) << 4);  // inverse-swizzled source col
  const int swc = ((c >> 1) & 3) << 4;             // read-side swizzle (row bits = c)

#define BARX() do { __builtin_amdgcn_s_barrier(); asm volatile("" ::: "memory"); } while (0)
#define STG(SRC, GROW0, LDS0) \
  gload_lds16((SRC) + (size_t)((GROW0) + lr) * Kd + k0n + scol, (LDS0) + lr * 64 + lcol)

  f32x4 acc[8][4] = {};

  {
    const int k0n = 0;
    u16* sAn = smem;
    u16* sBn = smem + 16384;
    STG(B, tn + 0, sBn); STG(B, tn + 64, sBn + 64 * 64);
    STG(B, tn + 128, sBn + 128 * 64); STG(B, tn + 192, sBn + 192 * 64);
    STG(A, tm + 0, sAn); STG(A, tm + 128, sAn + 128 * 64);
    STG(A, tm + 64, sAn + 64 * 64); STG(A, tm + 192, sAn + 192 * 64);
  }

  const int nt = Kd >> 6;
  for (int t = 0; t < nt; ++t) {
    const int slot = t & 1;
    u16* sAc = smem + slot * 32768;
    u16* sBc = sAc + 16384;
    u16* sAn = smem + (slot ^ 1) * 32768;
    u16* sBn = sAn + 16384;
    const int k0n = (t + 1) << 6;
    const bool st = (t + 1) < nt;

    bf16x8 bfr[4][2], af[2][2];

#define APH(q)                                                                  \
  do {                                                                          \
    _Pragma("unroll") for (int m2 = 0; m2 < 2; ++m2)                            \
    _Pragma("unroll") for (int kk = 0; kk < 2; ++kk)                            \
        af[m2][kk] = *(const bf16x8*)(sAc + (wr * 128 + (q) * 32 + m2 * 16 + c) * 64 + \
                                      ((kk * 32 + g * 8) ^ swc));               \
    __builtin_amdgcn_s_setprio(1);                                              \
    _Pragma("unroll") for (int m2 = 0; m2 < 2; ++m2)                            \
    _Pragma("unroll") for (int n = 0; n < 4; ++n)                               \
    _Pragma("unroll") for (int kk = 0; kk < 2; ++kk)                            \
        acc[(q) * 2 + m2][n] = __builtin_amdgcn_mfma_f32_16x16x32_bf16(         \
            af[m2][kk], bfr[n][kk], acc[(q) * 2 + m2][n], 0, 0, 0);             \
    __builtin_amdgcn_s_setprio(0);                                              \
  } while (0)

    // ---- q0 ----
    BARX();
    if (st) { STG(B, tn + 0, sBn); STG(B, tn + 64, sBn + 64 * 64); }
    if (st) asm volatile("s_waitcnt vmcnt(4)" ::: "memory");
    else    asm volatile("s_waitcnt vmcnt(2)" ::: "memory");
    BARX();
#pragma unroll
    for (int n = 0; n < 4; ++n)
#pragma unroll
      for (int kk = 0; kk < 2; ++kk)
        bfr[n][kk] = *(const bf16x8*)(sBc + (wc * 64 + n * 16 + c) * 64 +
                                      ((kk * 32 + g * 8) ^ swc));
    APH(0);
    // ---- q1 ----
    if (st) { STG(B, tn + 128, sBn + 128 * 64); STG(B, tn + 192, sBn + 192 * 64); }
    APH(1);
    // ---- q2 ----
    if (st) { STG(A, tm + 0, sAn); STG(A, tm + 128, sAn + 128 * 64); }
    if (st) asm volatile("s_waitcnt vmcnt(6)" ::: "memory");
    else    asm volatile("s_waitcnt vmcnt(0)" ::: "memory");
    BARX();
    APH(2);
    // ---- q3 ----
    if (st) { STG(A, tm + 64, sAn + 64 * 64); STG(A, tm + 192, sAn + 192 * 64); }
    APH(3);
#undef APH
  }

  if constexpr (OUT_MODE == 3) {
    if (tn >= 2048) {
      // ---- K/V fragment-order epilogue: scatter to 128KB LDS, then 16x8KB coalesced copy
      const bool isK = tn < 2560;
      BARX();
#pragma unroll
      for (int mi = 0; mi < 8; ++mi)
#pragma unroll
        for (int n = 0; n < 4; ++n)
#pragma unroll
          for (int i = 0; i < 4; ++i) {
            int s = wr * 128 + (mi >> 1) * 32 + (mi & 1) * 16 + g * 4 + i;  // kv row
            int e = wc * 64 + n * 16 + c;                                    // k or d col
            int chunk = (e >> 7) * 8 + (s >> 5);
            int off;
            if (isK) {
              int k = e & 127;
              off = chunk * 4096 + (k >> 4) * 512 + ((k >> 3) & 1) * 256 + (s & 31) * 8 + (k & 7);
            } else {
              int d = e & 127;
              off = chunk * 4096 + (((s >> 4) & 1) * 4 + (d >> 5)) * 512 + ((s >> 3) & 1) * 256 +
                    (d & 31) * 8 + (s & 7);
            }
            smem[off] = f2b(acc[mi][n][i]);
          }
      BARX();
      const int kvh_base = (tn - (isK ? 2048 : 2560)) >> 7;
      const int bb = tm >> 11;
      const int kvt0 = (tm & 2047) >> 5;
      u16* Out = isK ? Kout : Vout;
#pragma unroll
      for (int ch = 0; ch < 16; ++ch) {
        u16* dst = Out + (size_t)((bb * 4 + kvh_base + (ch >> 3)) * 64 + kvt0 + (ch & 7)) * 4096;
        *(bf16x8*)(dst + tid * 8) = *(const bf16x8*)(smem + ch * 4096 + tid * 8);
      }
      return;
    }
    // Q tiles: bf16 row-major, ld 2048
#pragma unroll
    for (int mi = 0; mi < 8; ++mi)
#pragma unroll
      for (int n = 0; n < 4; ++n)
#pragma unroll
        for (int i = 0; i < 4; ++i) {
          int row = tm + wr * 128 + (mi >> 1) * 32 + (mi & 1) * 16 + g * 4 + i;
          int col = tn + wc * 64 + n * 16 + c;
          ((u16*)Cout)[(size_t)row * 2048 + col] = f2b(acc[mi][n][i]);
        }
    return;
  }

  // OUT_MODE 2: fp32 row-major
#pragma unroll
  for (int mi = 0; mi < 8; ++mi)
#pragma unroll
    for (int n = 0; n < 4; ++n)
#pragma unroll
      for (int i = 0; i < 4; ++i) {
        int row = tm + wr * 128 + (mi >> 1) * 32 + (mi & 1) * 16 + g * 4 + i;
        int col = tn + wc * 64 + n * 16 + c;
        ((float*)Cout)[(size_t)row * N + col] = acc[mi][n][i];
      }
#undef STG
#undef BARX
}

// ---------------- 256x128 8-phase GEMM (O-proj): C[4096,2048] fp32 = A * B^T ----------------
// 96 KB LDS, grid (16,16)=256 blocks = 100% CU fill. Waits vmcnt(4)@q0, vmcnt(6)@q2.
__global__ __launch_bounds__(512) void gemm_op(const u16* __restrict__ A, const u16* __restrict__ B,
                                               float* __restrict__ Cout, int Kd) {
  __shared__ u16 smem[49152];  // 96 KB: [slot: A 16384 | B 8192] x 2
  const int tid = threadIdx.x;
  const int l = tid & 63, w = tid >> 6;
  const int c = l & 15, g = l >> 4;
  const int wr = w >> 2, wc = w & 3;
  const int tm = blockIdx.y * 256, tn = blockIdx.x * 128;

  const int lr = tid >> 3;
  const int lcol = (tid & 7) * 8;
  const int scol = lcol ^ (((lr >> 1) & 3) << 4);
  const int swc = ((c >> 1) & 3) << 4;

#define BARX() do { __builtin_amdgcn_s_barrier(); asm volatile("" ::: "memory"); } while (0)
#define STG(SRC, GROW0, LDS0) \
  gload_lds16((SRC) + (size_t)((GROW0) + lr) * Kd + k0n + scol, (LDS0) + lr * 64 + lcol)

  f32x4 acc[8][2] = {};

  {
    const int k0n = 0;
    u16* sAn = smem;
    u16* sBn = smem + 16384;
    STG(B, tn + 0, sBn); STG(B, tn + 64, sBn + 64 * 64);
    STG(A, tm + 0, sAn); STG(A, tm + 128, sAn + 128 * 64);
    STG(A, tm + 64, sAn + 64 * 64); STG(A, tm + 192, sAn + 192 * 64);
  }

  const int nt = Kd >> 6;
  for (int t = 0; t < nt; ++t) {
    const int slot = t & 1;
    u16* sAc = smem + slot * 24576;
    u16* sBc = sAc + 16384;
    u16* sAn = smem + (slot ^ 1) * 24576;
    u16* sBn = sAn + 16384;
    const int k0n = (t + 1) << 6;
    const bool st = (t + 1) < nt;

    bf16x8 bfr[2][2], af[2][2];

#define APH(q)                                                                  \
  do {                                                                          \
    _Pragma("unroll") for (int m2 = 0; m2 < 2; ++m2)                            \
    _Pragma("unroll") for (int kk = 0; kk < 2; ++kk)                            \
        af[m2][kk] = *(const bf16x8*)(sAc + (wr * 128 + (q) * 32 + m2 * 16 + c) * 64 + \
                                      ((kk * 32 + g * 8) ^ swc));               \
    __builtin_amdgcn_s_setprio(1);                                              \
    _Pragma("unroll") for (int m2 = 0; m2 < 2; ++m2)                            \
    _Pragma("unroll") for (int n = 0; n < 2; ++n)                               \
    _Pragma("unroll") for (int kk = 0; kk < 2; ++kk)                            \
        acc[(q) * 2 + m2][n] = __builtin_amdgcn_mfma_f32_16x16x32_bf16(         \
            af[m2][kk], bfr[n][kk], acc[(q) * 2 + m2][n], 0, 0, 0);             \
    __builtin_amdgcn_s_setprio(0);                                              \
  } while (0)

    // ---- q0 ----
    BARX();
    if (st) { STG(B, tn + 0, sBn); STG(B, tn + 64, sBn + 64 * 64); }
    if (st) asm volatile("s_waitcnt vmcnt(4)" ::: "memory");
    else    asm volatile("s_waitcnt vmcnt(2)" ::: "memory");
    BARX();
#pragma unroll
    for (int n = 0; n < 2; ++n)
#pragma unroll
      for (int kk = 0; kk < 2; ++kk)
        bfr[n][kk] = *(const bf16x8*)(sBc + (wc * 32 + n * 16 + c) * 64 +
                                      ((kk * 32 + g * 8) ^ swc));
    APH(0);
    // ---- q1 ----
    if (st) { STG(A, tm + 0, sAn); STG(A, tm + 128, sAn + 128 * 64); }
    APH(1);
    // ---- q2 ----
    if (st) { STG(A, tm + 64, sAn + 64 * 64); STG(A, tm + 192, sAn + 192 * 64); }
    if (st) asm volatile("s_waitcnt vmcnt(6)" ::: "memory");
    else    asm volatile("s_waitcnt vmcnt(0)" ::: "memory");
    BARX();
    APH(2);
    // ---- q3 ----
    APH(3);
#undef APH
  }

  // fp32 row-major epilogue (N = 2048)
#pragma unroll
  for (int mi = 0; mi < 8; ++mi)
#pragma unroll
    for (int n = 0; n < 2; ++n)
#pragma unroll
      for (int i = 0; i < 4; ++i) {
        int row = tm + wr * 128 + (mi >> 1) * 32 + (mi & 1) * 16 + g * 4 + i;
        int col = tn + wc * 32 + n * 16 + c;
        Cout[(size_t)row * 2048 + col] = acc[mi][n][i];
      }
#undef STG
#undef BARX
}

// ---------------- causal GQA flash attention: 32x32 swapped-operand, fully balanced ----
// grid (1024), block 256 (4 waves). XCD-affinity decode keeps each bh's K/V L2-local.
// TWO phases/block: subtile x, then 63-x; wave w takes kv-tiles (w+4i)*32; 2-stage merge.
// K/V MFMA-fragment-ordered: every load = 64 lanes x contiguous 16 B. V(cur) issued
// before K(next). [r19 post-mortem: 2-deep sacc pipeline spills (893 MB scratch writes,
// 5.4x regression) — this 4xf32x16-accumulator design has NO VGPR headroom for more
// in-flight tile state; the r18 single-sacc loop is the structural floor.]
// NOTE: min-waves arg MUST be 2 — (256,4) caps VGPR at 64 and spills (round 8).
__global__ __launch_bounds__(256, 2) void attn_fwd(const u16* __restrict__ Q, const u16* __restrict__ Kf,
                                                   const u16* __restrict__ Vf, u16* __restrict__ AO) {
  const int l = threadIdx.x & 63, w = threadIdx.x >> 6;
  const int ql = l & 31, hi = l >> 5;
  const int id = (int)blockIdx.x;
  const int xcd = id & 7, slot = id >> 3;
  const int bh = xcd + 8 * (slot >> 5);
  const int x = slot & 31;
  const int b = bh >> 4, h = bh & 15;
  const int kvh = h >> 2;

  __shared__ float4 mO[2][16][64];
  __shared__ float mML[2][2][64];

  const float sm = 0.08838834764831845f * 1.4426950408889634f;  // 1/sqrt(128) * log2(e)

  const u16* Kfb = Kf + (size_t)(b * 4 + kvh) * 64 * 4096 + l * 8;
  const u16* Vfb = Vf + (size_t)(b * 4 + kvh) * 64 * 4096 + l * 8;

#define LOADK(KF, KV0)                                                        \
  do {                                                                        \
    const u16* kb_ = Kfb + (size_t)((KV0) >> 5) * 4096;                       \
    _Pragma("unroll") for (int ck = 0; ck < 8; ++ck)                          \
        KF[ck] = *(const bf16x8*)(kb_ + ck * 512);                            \
  } while (0)

#define LOADV(VT, KV0)                                                        \
  do {                                                                        \
    const u16* vb_ = Vfb + (size_t)((KV0) >> 5) * 4096;                       \
    _Pragma("unroll") for (int ks = 0; ks < 2; ++ks)                          \
    _Pragma("unroll") for (int db = 0; db < 4; ++db)                          \
        VT[ks][db] = *(const bf16x8*)(vb_ + (ks * 4 + db) * 512);             \
  } while (0)

#define COMPUTE(KF, VT, KV0)                                                  \
  do {                                                                        \
    f32x16 sacc = {};                                                         \
    __builtin_amdgcn_s_setprio(1);                                            \
    _Pragma("unroll") for (int ck = 0; ck < 8; ++ck)                          \
        sacc = __builtin_amdgcn_mfma_f32_32x32x16_bf16(KF[ck], qf[ck], sacc, 0, 0, 0); \
    __builtin_amdgcn_s_setprio(0);                                            \
    if ((KV0) == q0) { /* diagonal: mask kv > q */                            \
      _Pragma("unroll") for (int r = 0; r < 16; ++r) {                        \
        int crow = (r & 3) + 8 * (r >> 2) + 4 * hi;                           \
        if (crow > ql) sacc[r] = -1e30f;                                      \
      }                                                                       \
    }                                                                         \
    float t0 = fmaxf(sacc[0], sacc[1]), t1 = fmaxf(sacc[2], sacc[3]);         \
    float t2 = fmaxf(sacc[4], sacc[5]), t3 = fmaxf(sacc[6], sacc[7]);         \
    float t4 = fmaxf(sacc[8], sacc[9]), t5 = fmaxf(sacc[10], sacc[11]);       \
    float t6 = fmaxf(sacc[12], sacc[13]), t7 = fmaxf(sacc[14], sacc[15]);     \
    float mx = fmaxf(fmaxf(fmaxf(t0, t1), fmaxf(t2, t3)),                     \
                     fmaxf(fmaxf(t4, t5), fmaxf(t6, t7)));                    \
    mx = xhalf_max(mx);                                                       \
    float p[16];                                                              \
    _Pragma("unroll") for (int r = 0; r < 16; ++r)                            \
        p[r] = exp2f((sacc[r] - mrow) * sm);                                  \
    if (!__all((mx - mrow) * sm <= 8.0f)) { /* T13 defer-max */               \
      float mnew = fmaxf(mrow, mx);                                           \
      float rs = exp2f((mrow - mnew) * sm);                                   \
      mrow = mnew;                                                            \
      lrow *= rs;                                                             \
      _Pragma("unroll") for (int db = 0; db < 4; ++db)                        \
      _Pragma("unroll") for (int r = 0; r < 16; ++r) acc[db][r] *= rs;        \
      _Pragma("unroll") for (int r = 0; r < 16; ++r)                          \
          p[r] = exp2f((sacc[r] - mrow) * sm);                                \
    }                                                                         \
    float s0 = p[0] + p[1], s1 = p[2] + p[3], s2 = p[4] + p[5], s3 = p[6] + p[7]; \
    float s4 = p[8] + p[9], s5 = p[10] + p[11], s6 = p[12] + p[13], s7 = p[14] + p[15]; \
    float psum = ((s0 + s1) + (s2 + s3)) + ((s4 + s5) + (s6 + s7));           \
    lrow += xhalf_sum(psum);                                                  \
    u32 a0 = pktrunc(p[0], p[1]), a1 = pktrunc(p[2], p[3]);                   \
    u32 a2 = pktrunc(p[4], p[5]), a3 = pktrunc(p[6], p[7]);                   \
    u32 b0 = pktrunc(p[8], p[9]), b1 = pktrunc(p[10], p[11]);                 \
    u32 b2 = pktrunc(p[12], p[13]), b3 = pktrunc(p[14], p[15]);               \
    union { bf16x8 v; u32 u[4]; } pa0, pa1;                                   \
    xexchange(hi, a0, a1, a2, a3, pa0.u);                                     \
    xexchange(hi, b0, b1, b2, b3, pa1.u);                                     \
    __builtin_amdgcn_s_setprio(1);                                            \
    _Pragma("unroll") for (int db = 0; db < 4; ++db) {                        \
      acc[db] = __builtin_amdgcn_mfma_f32_32x32x16_bf16(VT[0][db], pa0.v, acc[db], 0, 0, 0); \
      acc[db] = __builtin_amdgcn_mfma_f32_32x32x16_bf16(VT[1][db], pa1.v, acc[db], 0, 0, 0); \
    }                                                                         \
    __builtin_amdgcn_s_setprio(0);                                            \
  } while (0)

#define PUBLISH(SLOT)                                                         \
  do {                                                                        \
    _Pragma("unroll") for (int db = 0; db < 4; ++db)                          \
    _Pragma("unroll") for (int rq = 0; rq < 4; ++rq) {                        \
      float4 v;                                                               \
      v.x = acc[db][rq * 4 + 0];                                              \
      v.y = acc[db][rq * 4 + 1];                                              \
      v.z = acc[db][rq * 4 + 2];                                              \
      v.w = acc[db][rq * 4 + 3];                                              \
      mO[SLOT][db * 4 + rq][l] = v;                                           \
    }                                                                         \
    mML[SLOT][0][l] = mrow;                                                   \
    mML[SLOT][1][l] = lrow;                                                   \
  } while (0)

#define MERGE(SLOT)                                                           \
  do {                                                                        \
    float m1 = mML[SLOT][0][l], l1 = mML[SLOT][1][l];                         \
    float mnew = fmaxf(mrow, m1);                                             \
    float f0 = exp2f((mrow - mnew) * sm);                                     \
    float f1 = exp2f((m1 - mnew) * sm);                                       \
    mrow = mnew;                                                              \
    lrow = lrow * f0 + l1 * f1;                                               \
    _Pragma("unroll") for (int db = 0; db < 4; ++db)                          \
    _Pragma("unroll") for (int rq = 0; rq < 4; ++rq) {                        \
      float4 o1 = mO[SLOT][db * 4 + rq][l];                                   \
      acc[db][rq * 4 + 0] = acc[db][rq * 4 + 0] * f0 + o1.x * f1;             \
      acc[db][rq * 4 + 1] = acc[db][rq * 4 + 1] * f0 + o1.y * f1;             \
      acc[db][rq * 4 + 2] = acc[db][rq * 4 + 2] * f0 + o1.z * f1;             \
      acc[db][rq * 4 + 3] = acc[db][rq * 4 + 3] * f0 + o1.w * f1;             \
    }                                                                         \
  } while (0)

  for (int phase = 0; phase < 2; ++phase) {
    const int t = phase ? (63 - x) : x;
    const int q0 = t * 32;

    bf16x8 qf[8];
    {
      const u16* qb = Q + ((size_t)(b * 2048 + q0 + ql)) * 2048 + h * 128 + hi * 8;
#pragma unroll
      for (int ck = 0; ck < 8; ++ck) qf[ck] = *(const bf16x8*)(qb + ck * 16);
    }

    f32x16 acc[4] = {};
    float mrow = -1e30f, lrow = 0.f;

    bf16x8 kfa[8], kfb[8];
    bf16x8 vt[2][4];

    int kv0 = w * 32;
    if (kv0 <= q0) {
      LOADK(kfa, kv0);
      while (true) {
        LOADV(vt, kv0);                       // V(cur) first (issue order)
        bool more = kv0 + 128 <= q0;
        if (more) LOADK(kfb, kv0 + 128);      // K(next) after V(cur)
        COMPUTE(kfa, vt, kv0);
        if (!more) break;
        kv0 += 128;
        LOADV(vt, kv0);
        more = kv0 + 128 <= q0;
        if (more) LOADK(kfa, kv0 + 128);
        COMPUTE(kfb, vt, kv0);
        if (!more) break;
        kv0 += 128;
      }
    }

    if (w >= 2) PUBLISH(w - 2);
    __syncthreads();
    if (w < 2) MERGE(w);
    __syncthreads();
    if (w == 1) PUBLISH(0);
    __syncthreads();
    if (w == 0) {
      MERGE(0);
      float inv = 1.0f / lrow;
      u16* ob = AO + (size_t)(b * 2048 + q0 + ql) * 2048 + h * 128 + hi * 4;
#pragma unroll
      for (int db = 0; db < 4; ++db)
#pragma unroll
        for (int rq = 0; rq < 4; ++rq) {
          ushort4 o;
          o.x = f2b(acc[db][rq * 4 + 0] * inv);
          o.y = f2b(acc[db][rq * 4 + 1] * inv);
          o.z = f2b(acc[db][rq * 4 + 2] * inv);
          o.w = f2b(acc[db][rq * 4 + 3] * inv);
          *(ushort4*)(ob + db * 32 + rq * 8) = o;
        }
    }
    __syncthreads();  // slot reuse guard before next phase's PUBLISH
  }
#undef LOADK
#undef LOADV
#undef COMPUTE
#undef PUBLISH
#undef MERGE
}

// ---------------- host ----------------
extern "C" void kernel_launch(void* const* d_in, const int* in_sizes, int n_in,
                              void* d_out, int out_size, void* d_ws, size_t ws_size,
                              hipStream_t stream) {
  const float* X = (const float*)d_in[0];
  const float* Wq = (const float*)d_in[1];
  const float* Wk = (const float*)d_in[2];
  const float* Wv = (const float*)d_in[3];
  const float* Wo = (const float*)d_in[4];

  u16* ws = (u16*)d_ws;
  const size_t nX = 8388608;   // 2*2048*2048
  const size_t nWq = 4194304;  // 2048*2048
  const size_t nWk = 1048576;  // 512*2048
  u16* Xb = ws;
  u16* Wqb = Xb + nX;          // [Wq|Wk|Wv] contiguous = fused 3072x2048 weight
  u16* Wkb = Wqb + nWq;
  u16* Wvb = Wkb + nWk;
  u16* Wob = Wvb + nWk;
  u16* Qb = Wob + nWq;
  u16* Kfb = Qb + nX;          // K in fragment order (2M u16)
  u16* Vfb = Kfb + 2097152;    // V in fragment order (2M u16)
  u16* AOb = Vfb + 2097152;
  if (ws_size < (size_t)(39845888) * 2) return;

  // fused fp32->bf16: X + Wq + Wk + Wv (Wo converted by gemm256's 64 aux blocks)
  cvt_all<<<2048, 256, 0, stream>>>(X, Wq, Wk, Wv, Xb);

  // fused QKV projection (256^2 8-phase) + Wo conversion on spare blocks
  gemm256<3><<<dim3(16, 16), 512, 0, stream>>>(Xb, Wqb, Qb, 4096, 3072, 2048, Kfb, Vfb,
                                               Wo, Wob);

  attn_fwd<<<dim3(1024), 256, 0, stream>>>(Qb, Kfb, Vfb, AOb);

  // output projection (256x128 8-phase, 256 blocks = full chip) -> fp32 d_out
  gemm_op<<<dim3(16, 16), 512, 0, stream>>>(AOb, Wob, (float*)d_out, 2048);
}

// Round 21
// 188.938 us; speedup vs baseline: 2.7140x; 1.0075x over previous
//
#include <hip/hip_runtime.h>

typedef unsigned short u16;
typedef unsigned int u32;
typedef __attribute__((ext_vector_type(4))) float f32x4;
typedef __attribute__((ext_vector_type(16))) float f32x16;
typedef __attribute__((ext_vector_type(8))) short bf16x8;

// Problem sizes (fixed): B=2, S=2048, D=2048, NH=16, NKV=4, HD=128
// Softmax scale (1/sqrt(128) * log2(e)) is FOLDED INTO Q at the QKV epilogue (r21):
// attention operates entirely in pre-scaled log2 units, removing ~16 v_mul per
// 32x32 tile (VALU was 2.4x the MFMA issue time; this is the dominant-axis cut).
#define QSC (0.08838834764831845f * 1.4426950408889634f)

__device__ __forceinline__ u16 f2b(float f) {
  u32 u = __builtin_bit_cast(u32, f);
  u = (u + 0x7fffu + ((u >> 16) & 1u)) >> 16;  // RNE
  return (u16)u;
}

__device__ __forceinline__ void gload_lds16(const void* g, void* l) {
  __builtin_amdgcn_global_load_lds((const __attribute__((address_space(1))) u32*)g,
                                   (__attribute__((address_space(3))) u32*)l, 16, 0, 0);
}

// ---- cross-half (lane <-> lane^32) exchange via v_permlane32_swap_b32 (VALU pipe) ----
#if __has_builtin(__builtin_amdgcn_permlane32_swap)
#define HAS_PLS 1
__device__ __forceinline__ void pls(u32 x, u32 y, u32& rx, u32& ry) {
  auto r = __builtin_amdgcn_permlane32_swap(x, y, false, false);
  rx = (u32)r[0];
  ry = (u32)r[1];
}
#endif

__device__ __forceinline__ float xhalf_max(float v) {
#ifdef HAS_PLS
  u32 a, b;
  pls(__builtin_bit_cast(u32, v), __builtin_bit_cast(u32, v), a, b);
  return fmaxf(__builtin_bit_cast(float, a), __builtin_bit_cast(float, b));
#else
  return fmaxf(v, __shfl_xor(v, 32));
#endif
}

__device__ __forceinline__ float xhalf_sum(float v) {
#ifdef HAS_PLS
  u32 a, b;
  pls(__builtin_bit_cast(u32, v), __builtin_bit_cast(u32, v), a, b);
  return __builtin_bit_cast(float, a) + __builtin_bit_cast(float, b);
#else
  return v + __shfl_xor(v, 32);
#endif
}

// P-fragment redistribution across lane halves
__device__ __forceinline__ void xexchange(int hi, u32 a0, u32 a1, u32 a2, u32 a3, u32* o) {
#ifdef HAS_PLS
  pls(a0, a2, o[0], o[2]);
  pls(a1, a3, o[1], o[3]);
#else
  u32 xa0 = (u32)__shfl_xor((int)a0, 32), xa1 = (u32)__shfl_xor((int)a1, 32);
  u32 xa2 = (u32)__shfl_xor((int)a2, 32), xa3 = (u32)__shfl_xor((int)a3, 32);
  o[0] = hi ? xa2 : a0;
  o[1] = hi ? xa3 : a1;
  o[2] = hi ? a2 : xa0;
  o[3] = hi ? a3 : xa1;
#endif
}

// truncating bf16 pair pack (P in [0,1]; <=2^-8 rel err, cheap: 3 ops)
__device__ __forceinline__ u32 pktrunc(float lo, float hif) {
  return (__builtin_bit_cast(u32, lo) >> 16) | (__builtin_bit_cast(u32, hif) & 0xffff0000u);
}

// ---------------- fused fp32 -> bf16 conversion: X + Wq + Wk + Wv in one launch ----------------
// dst layout (contiguous): [Xb 8388608 | Wqb 4194304 | Wkb 1048576 | Wvb 1048576]
__global__ void cvt_all(const float* __restrict__ X, const float* __restrict__ Wq,
                        const float* __restrict__ Wk, const float* __restrict__ Wv,
                        u16* __restrict__ dst) {
  const int total = 14680064;
  int stride = gridDim.x * blockDim.x * 4;
  for (int idx = (blockIdx.x * blockDim.x + threadIdx.x) * 4; idx < total; idx += stride) {
    const float* src;
    int off;
    if (idx < 8388608) { src = X; off = idx; }
    else if (idx < 12582912) { src = Wq; off = idx - 8388608; }
    else if (idx < 13631488) { src = Wk; off = idx - 12582912; }
    else { src = Wv; off = idx - 13631488; }
    float4 v = *(const float4*)(src + off);
    ushort4 o;
    o.x = f2b(v.x); o.y = f2b(v.y); o.z = f2b(v.z); o.w = f2b(v.w);
    *(ushort4*)(dst + idx) = o;
  }
}

// ---------------- 256x256 8-phase GEMM (QKV): C[M,N] = A[M,K] * B[N,K]^T ----------------
// grid (16,16): blockIdx.x < 12 -> GEMM N-tile; blockIdx.x >= 12 -> 64 aux blocks convert
// Wo fp32->bf16 (fills the 64 CUs the 192-block GEMM leaves idle). 512 threads, BK=64,
// 128 KB LDS dbuf, T2 XOR-swizzle both-sides, counted vmcnt (4@q0 / 6@q2), raw s_barrier,
// T5 setprio. OUT_MODE 3 = fused QKV routing (Q row-major PRE-SCALED by QSC, K/V fragment
// order via LDS-staged epilogue).
template<int OUT_MODE>
__global__ __launch_bounds__(512) void gemm256(const u16* __restrict__ A, const u16* __restrict__ B,
                                               void* __restrict__ Cout, int M, int N, int Kd,
                                               u16* __restrict__ Kout, u16* __restrict__ Vout,
                                               const float* __restrict__ WoSrc,
                                               u16* __restrict__ WoDst) {
  __shared__ u16 smem[65536];  // 128 KB: [slot0: A 16384 | B 16384][slot1: ...]
  const int tid = threadIdx.x;

  if constexpr (OUT_MODE == 3) {
    if (blockIdx.x >= 12) {  // aux: Wo conversion (4194304 elems over 64 blocks)
      const int id = ((int)blockIdx.x - 12) * (int)gridDim.y + (int)blockIdx.y;
      const int base = id * 65536;
#pragma unroll 4
      for (int j = tid * 4; j < 65536; j += 2048) {
        float4 v = *(const float4*)(WoSrc + base + j);
        ushort4 o;
        o.x = f2b(v.x); o.y = f2b(v.y); o.z = f2b(v.z); o.w = f2b(v.w);
        *(ushort4*)(WoDst + base + j) = o;
      }
      return;
    }
  }

  const int l = tid & 63, w = tid >> 6;
  const int c = l & 15, g = l >> 4;
  const int wr = w >> 2, wc = w & 3;
  const int tm = blockIdx.y * 256, tn = blockIdx.x * 256;

  const int lr = tid >> 3;           // row within round
  const int lcol = (tid & 7) * 8;    // dest u16 col
  const int scol = lcol ^ (((lr >> 1) & 3) << 4);  // inverse-swizzled source col
  const int swc = ((c >> 1) & 3) << 4;             // read-side swizzle (row bits = c)

#define BARX() do { __builtin_amdgcn_s_barrier(); asm volatile("" ::: "memory"); } while (0)
#define STG(SRC, GROW0, LDS0) \
  gload_lds16((SRC) + (size_t)((GROW0) + lr) * Kd + k0n + scol, (LDS0) + lr * 64 + lcol)

  f32x4 acc[8][4] = {};

  {
    const int k0n = 0;
    u16* sAn = smem;
    u16* sBn = smem + 16384;
    STG(B, tn + 0, sBn); STG(B, tn + 64, sBn + 64 * 64);
    STG(B, tn + 128, sBn + 128 * 64); STG(B, tn + 192, sBn + 192 * 64);
    STG(A, tm + 0, sAn); STG(A, tm + 128, sAn + 128 * 64);
    STG(A, tm + 64, sAn + 64 * 64); STG(A, tm + 192, sAn + 192 * 64);
  }

  const int nt = Kd >> 6;
  for (int t = 0; t < nt; ++t) {
    const int slot = t & 1;
    u16* sAc = smem + slot * 32768;
    u16* sBc = sAc + 16384;
    u16* sAn = smem + (slot ^ 1) * 32768;
    u16* sBn = sAn + 16384;
    const int k0n = (t + 1) << 6;
    const bool st = (t + 1) < nt;

    bf16x8 bfr[4][2], af[2][2];

#define APH(q)                                                                  \
  do {                                                                          \
    _Pragma("unroll") for (int m2 = 0; m2 < 2; ++m2)                            \
    _Pragma("unroll") for (int kk = 0; kk < 2; ++kk)                            \
        af[m2][kk] = *(const bf16x8*)(sAc + (wr * 128 + (q) * 32 + m2 * 16 + c) * 64 + \
                                      ((kk * 32 + g * 8) ^ swc));               \
    __builtin_amdgcn_s_setprio(1);                                              \
    _Pragma("unroll") for (int m2 = 0; m2 < 2; ++m2)                            \
    _Pragma("unroll") for (int n = 0; n < 4; ++n)                               \
    _Pragma("unroll") for (int kk = 0; kk < 2; ++kk)                            \
        acc[(q) * 2 + m2][n] = __builtin_amdgcn_mfma_f32_16x16x32_bf16(         \
            af[m2][kk], bfr[n][kk], acc[(q) * 2 + m2][n], 0, 0, 0);             \
    __builtin_amdgcn_s_setprio(0);                                              \
  } while (0)

    // ---- q0 ----
    BARX();
    if (st) { STG(B, tn + 0, sBn); STG(B, tn + 64, sBn + 64 * 64); }
    if (st) asm volatile("s_waitcnt vmcnt(4)" ::: "memory");
    else    asm volatile("s_waitcnt vmcnt(2)" ::: "memory");
    BARX();
#pragma unroll
    for (int n = 0; n < 4; ++n)
#pragma unroll
      for (int kk = 0; kk < 2; ++kk)
        bfr[n][kk] = *(const bf16x8*)(sBc + (wc * 64 + n * 16 + c) * 64 +
                                      ((kk * 32 + g * 8) ^ swc));
    APH(0);
    // ---- q1 ----
    if (st) { STG(B, tn + 128, sBn + 128 * 64); STG(B, tn + 192, sBn + 192 * 64); }
    APH(1);
    // ---- q2 ----
    if (st) { STG(A, tm + 0, sAn); STG(A, tm + 128, sAn + 128 * 64); }
    if (st) asm volatile("s_waitcnt vmcnt(6)" ::: "memory");
    else    asm volatile("s_waitcnt vmcnt(0)" ::: "memory");
    BARX();
    APH(2);
    // ---- q3 ----
    if (st) { STG(A, tm + 64, sAn + 64 * 64); STG(A, tm + 192, sAn + 192 * 64); }
    APH(3);
#undef APH
  }

  if constexpr (OUT_MODE == 3) {
    if (tn >= 2048) {
      // ---- K/V fragment-order epilogue: scatter to 128KB LDS, then 16x8KB coalesced copy
      const bool isK = tn < 2560;
      BARX();
#pragma unroll
      for (int mi = 0; mi < 8; ++mi)
#pragma unroll
        for (int n = 0; n < 4; ++n)
#pragma unroll
          for (int i = 0; i < 4; ++i) {
            int s = wr * 128 + (mi >> 1) * 32 + (mi & 1) * 16 + g * 4 + i;  // kv row
            int e = wc * 64 + n * 16 + c;                                    // k or d col
            int chunk = (e >> 7) * 8 + (s >> 5);
            int off;
            if (isK) {
              int k = e & 127;
              off = chunk * 4096 + (k >> 4) * 512 + ((k >> 3) & 1) * 256 + (s & 31) * 8 + (k & 7);
            } else {
              int d = e & 127;
              off = chunk * 4096 + (((s >> 4) & 1) * 4 + (d >> 5)) * 512 + ((s >> 3) & 1) * 256 +
                    (d & 31) * 8 + (s & 7);
            }
            smem[off] = f2b(acc[mi][n][i]);
          }
      BARX();
      const int kvh_base = (tn - (isK ? 2048 : 2560)) >> 7;
      const int bb = tm >> 11;
      const int kvt0 = (tm & 2047) >> 5;
      u16* Out = isK ? Kout : Vout;
#pragma unroll
      for (int ch = 0; ch < 16; ++ch) {
        u16* dst = Out + (size_t)((bb * 4 + kvh_base + (ch >> 3)) * 64 + kvt0 + (ch & 7)) * 4096;
        *(bf16x8*)(dst + tid * 8) = *(const bf16x8*)(smem + ch * 4096 + tid * 8);
      }
      return;
    }
    // Q tiles: bf16 row-major, ld 2048, PRE-SCALED by QSC (softmax scale folded in)
#pragma unroll
    for (int mi = 0; mi < 8; ++mi)
#pragma unroll
      for (int n = 0; n < 4; ++n)
#pragma unroll
        for (int i = 0; i < 4; ++i) {
          int row = tm + wr * 128 + (mi >> 1) * 32 + (mi & 1) * 16 + g * 4 + i;
          int col = tn + wc * 64 + n * 16 + c;
          ((u16*)Cout)[(size_t)row * 2048 + col] = f2b(acc[mi][n][i] * QSC);
        }
    return;
  }

  // OUT_MODE 2: fp32 row-major
#pragma unroll
  for (int mi = 0; mi < 8; ++mi)
#pragma unroll
    for (int n = 0; n < 4; ++n)
#pragma unroll
      for (int i = 0; i < 4; ++i) {
        int row = tm + wr * 128 + (mi >> 1) * 32 + (mi & 1) * 16 + g * 4 + i;
        int col = tn + wc * 64 + n * 16 + c;
        ((float*)Cout)[(size_t)row * N + col] = acc[mi][n][i];
      }
#undef STG
#undef BARX
}

// ---------------- 256x128 8-phase GEMM (O-proj): C[4096,2048] fp32 = A * B^T ----------------
// 96 KB LDS, grid (16,16)=256 blocks = 100% CU fill. Waits vmcnt(4)@q0, vmcnt(6)@q2.
__global__ __launch_bounds__(512) void gemm_op(const u16* __restrict__ A, const u16* __restrict__ B,
                                               float* __restrict__ Cout, int Kd) {
  __shared__ u16 smem[49152];  // 96 KB: [slot: A 16384 | B 8192] x 2
  const int tid = threadIdx.x;
  const int l = tid & 63, w = tid >> 6;
  const int c = l & 15, g = l >> 4;
  const int wr = w >> 2, wc = w & 3;
  const int tm = blockIdx.y * 256, tn = blockIdx.x * 128;

  const int lr = tid >> 3;
  const int lcol = (tid & 7) * 8;
  const int scol = lcol ^ (((lr >> 1) & 3) << 4);
  const int swc = ((c >> 1) & 3) << 4;

#define BARX() do { __builtin_amdgcn_s_barrier(); asm volatile("" ::: "memory"); } while (0)
#define STG(SRC, GROW0, LDS0) \
  gload_lds16((SRC) + (size_t)((GROW0) + lr) * Kd + k0n + scol, (LDS0) + lr * 64 + lcol)

  f32x4 acc[8][2] = {};

  {
    const int k0n = 0;
    u16* sAn = smem;
    u16* sBn = smem + 16384;
    STG(B, tn + 0, sBn); STG(B, tn + 64, sBn + 64 * 64);
    STG(A, tm + 0, sAn); STG(A, tm + 128, sAn + 128 * 64);
    STG(A, tm + 64, sAn + 64 * 64); STG(A, tm + 192, sAn + 192 * 64);
  }

  const int nt = Kd >> 6;
  for (int t = 0; t < nt; ++t) {
    const int slot = t & 1;
    u16* sAc = smem + slot * 24576;
    u16* sBc = sAc + 16384;
    u16* sAn = smem + (slot ^ 1) * 24576;
    u16* sBn = sAn + 16384;
    const int k0n = (t + 1) << 6;
    const bool st = (t + 1) < nt;

    bf16x8 bfr[2][2], af[2][2];

#define APH(q)                                                                  \
  do {                                                                          \
    _Pragma("unroll") for (int m2 = 0; m2 < 2; ++m2)                            \
    _Pragma("unroll") for (int kk = 0; kk < 2; ++kk)                            \
        af[m2][kk] = *(const bf16x8*)(sAc + (wr * 128 + (q) * 32 + m2 * 16 + c) * 64 + \
                                      ((kk * 32 + g * 8) ^ swc));               \
    __builtin_amdgcn_s_setprio(1);                                              \
    _Pragma("unroll") for (int m2 = 0; m2 < 2; ++m2)                            \
    _Pragma("unroll") for (int n = 0; n < 2; ++n)                               \
    _Pragma("unroll") for (int kk = 0; kk < 2; ++kk)                            \
        acc[(q) * 2 + m2][n] = __builtin_amdgcn_mfma_f32_16x16x32_bf16(         \
            af[m2][kk], bfr[n][kk], acc[(q) * 2 + m2][n], 0, 0, 0);             \
    __builtin_amdgcn_s_setprio(0);                                              \
  } while (0)

    // ---- q0 ----
    BARX();
    if (st) { STG(B, tn + 0, sBn); STG(B, tn + 64, sBn + 64 * 64); }
    if (st) asm volatile("s_waitcnt vmcnt(4)" ::: "memory");
    else    asm volatile("s_waitcnt vmcnt(2)" ::: "memory");
    BARX();
#pragma unroll
    for (int n = 0; n < 2; ++n)
#pragma unroll
      for (int kk = 0; kk < 2; ++kk)
        bfr[n][kk] = *(const bf16x8*)(sBc + (wc * 32 + n * 16 + c) * 64 +
                                      ((kk * 32 + g * 8) ^ swc));
    APH(0);
    // ---- q1 ----
    if (st) { STG(A, tm + 0, sAn); STG(A, tm + 128, sAn + 128 * 64); }
    APH(1);
    // ---- q2 ----
    if (st) { STG(A, tm + 64, sAn + 64 * 64); STG(A, tm + 192, sAn + 192 * 64); }
    if (st) asm volatile("s_waitcnt vmcnt(6)" ::: "memory");
    else    asm volatile("s_waitcnt vmcnt(0)" ::: "memory");
    BARX();
    APH(2);
    // ---- q3 ----
    APH(3);
#undef APH
  }

  // fp32 row-major epilogue (N = 2048)
#pragma unroll
  for (int mi = 0; mi < 8; ++mi)
#pragma unroll
    for (int n = 0; n < 2; ++n)
#pragma unroll
      for (int i = 0; i < 4; ++i) {
        int row = tm + wr * 128 + (mi >> 1) * 32 + (mi & 1) * 16 + g * 4 + i;
        int col = tn + wc * 32 + n * 16 + c;
        Cout[(size_t)row * 2048 + col] = acc[mi][n][i];
      }
#undef STG
#undef BARX
}

// ---------------- causal GQA flash attention: 32x32 swapped-operand, fully balanced ----
// grid (1024), block 256 (4 waves). XCD-affinity decode keeps each bh's K/V L2-local.
// TWO phases/block: subtile x, then 63-x; wave w takes kv-tiles (w+4i)*32; 2-stage merge.
// K/V MFMA-fragment-ordered. Q is PRE-SCALED by QSC at the QKV epilogue -> the whole
// kernel runs in log2 units: p = exp2(sacc - m), defer-check (mx - m <= 8), merge
// factors exp2(m - mnew). Removes ~16 v_mul/tile from the dominant VALU axis (42% busy
// vs 18% MFMA).
// NOTE: min-waves arg MUST be 2 — (256,4) caps VGPR at 64 and spills (round 8).
// [r19: 2-deep sacc pipeline spills — no VGPR headroom for more in-flight tile state.]
__global__ __launch_bounds__(256, 2) void attn_fwd(const u16* __restrict__ Q, const u16* __restrict__ Kf,
                                                   const u16* __restrict__ Vf, u16* __restrict__ AO) {
  const int l = threadIdx.x & 63, w = threadIdx.x >> 6;
  const int ql = l & 31, hi = l >> 5;
  const int id = (int)blockIdx.x;
  const int xcd = id & 7, slot = id >> 3;
  const int bh = xcd + 8 * (slot >> 5);
  const int x = slot & 31;
  const int b = bh >> 4, h = bh & 15;
  const int kvh = h >> 2;

  __shared__ float4 mO[2][16][64];
  __shared__ float mML[2][2][64];

  const u16* Kfb = Kf + (size_t)(b * 4 + kvh) * 64 * 4096 + l * 8;
  const u16* Vfb = Vf + (size_t)(b * 4 + kvh) * 64 * 4096 + l * 8;

#define LOADK(KF, KV0)                                                        \
  do {                                                                        \
    const u16* kb_ = Kfb + (size_t)((KV0) >> 5) * 4096;                       \
    _Pragma("unroll") for (int ck = 0; ck < 8; ++ck)                          \
        KF[ck] = *(const bf16x8*)(kb_ + ck * 512);                            \
  } while (0)

#define LOADV(VT, KV0)                                                        \
  do {                                                                        \
    const u16* vb_ = Vfb + (size_t)((KV0) >> 5) * 4096;                       \
    _Pragma("unroll") for (int ks = 0; ks < 2; ++ks)                          \
    _Pragma("unroll") for (int db = 0; db < 4; ++db)                          \
        VT[ks][db] = *(const bf16x8*)(vb_ + (ks * 4 + db) * 512);             \
  } while (0)

#define COMPUTE(KF, VT, KV0)                                                  \
  do {                                                                        \
    f32x16 sacc = {};                                                         \
    __builtin_amdgcn_s_setprio(1);                                            \
    _Pragma("unroll") for (int ck = 0; ck < 8; ++ck)                          \
        sacc = __builtin_amdgcn_mfma_f32_32x32x16_bf16(KF[ck], qf[ck], sacc, 0, 0, 0); \
    __builtin_amdgcn_s_setprio(0);                                            \
    if ((KV0) == q0) { /* diagonal: mask kv > q */                            \
      _Pragma("unroll") for (int r = 0; r < 16; ++r) {                        \
        int crow = (r & 3) + 8 * (r >> 2) + 4 * hi;                           \
        if (crow > ql) sacc[r] = -1e30f;                                      \
      }                                                                       \
    }                                                                         \
    float t0 = fmaxf(sacc[0], sacc[1]), t1 = fmaxf(sacc[2], sacc[3]);         \
    float t2 = fmaxf(sacc[4], sacc[5]), t3 = fmaxf(sacc[6], sacc[7]);         \
    float t4 = fmaxf(sacc[8], sacc[9]), t5 = fmaxf(sacc[10], sacc[11]);       \
    float t6 = fmaxf(sacc[12], sacc[13]), t7 = fmaxf(sacc[14], sacc[15]);     \
    float mx = fmaxf(fmaxf(fmaxf(t0, t1), fmaxf(t2, t3)),                     \
                     fmaxf(fmaxf(t4, t5), fmaxf(t6, t7)));                    \
    mx = xhalf_max(mx);                                                       \
    float p[16];                                                              \
    _Pragma("unroll") for (int r = 0; r < 16; ++r)                            \
        p[r] = exp2f(sacc[r] - mrow);                                         \
    if (!__all(mx - mrow <= 8.0f)) { /* T13 defer-max (log2 units) */         \
      float mnew = fmaxf(mrow, mx);                                           \
      float rs = exp2f(mrow - mnew);                                          \
      mrow = mnew;                                                            \
      lrow *= rs;                                                             \
      _Pragma("unroll") for (int db = 0; db < 4; ++db)                        \
      _Pragma("unroll") for (int r = 0; r < 16; ++r) acc[db][r] *= rs;        \
      _Pragma("unroll") for (int r = 0; r < 16; ++r)                          \
          p[r] = exp2f(sacc[r] - mrow);                                       \
    }                                                                         \
    float s0 = p[0] + p[1], s1 = p[2] + p[3], s2 = p[4] + p[5], s3 = p[6] + p[7]; \
    float s4 = p[8] + p[9], s5 = p[10] + p[11], s6 = p[12] + p[13], s7 = p[14] + p[15]; \
    float psum = ((s0 + s1) + (s2 + s3)) + ((s4 + s5) + (s6 + s7));           \
    lrow += xhalf_sum(psum);                                                  \
    u32 a0 = pktrunc(p[0], p[1]), a1 = pktrunc(p[2], p[3]);                   \
    u32 a2 = pktrunc(p[4], p[5]), a3 = pktrunc(p[6], p[7]);                   \
    u32 b0 = pktrunc(p[8], p[9]), b1 = pktrunc(p[10], p[11]);                 \
    u32 b2 = pktrunc(p[12], p[13]), b3 = pktrunc(p[14], p[15]);               \
    union { bf16x8 v; u32 u[4]; } pa0, pa1;                                   \
    xexchange(hi, a0, a1, a2, a3, pa0.u);                                     \
    xexchange(hi, b0, b1, b2, b3, pa1.u);                                     \
    __builtin_amdgcn_s_setprio(1);                                            \
    _Pragma("unroll") for (int db = 0; db < 4; ++db) {                        \
      acc[db] = __builtin_amdgcn_mfma_f32_32x32x16_bf16(VT[0][db], pa0.v, acc[db], 0, 0, 0); \
      acc[db] = __builtin_amdgcn_mfma_f32_32x32x16_bf16(VT[1][db], pa1.v, acc[db], 0, 0, 0); \
    }                                                                         \
    __builtin_amdgcn_s_setprio(0);                                            \
  } while (0)

#define PUBLISH(SLOT)                                                         \
  do {                                                                        \
    _Pragma("unroll") for (int db = 0; db < 4; ++db)                          \
    _Pragma("unroll") for (int rq = 0; rq < 4; ++rq) {                        \
      float4 v;                                                               \
      v.x = acc[db][rq * 4 + 0];                                              \
      v.y = acc[db][rq * 4 + 1];                                              \
      v.z = acc[db][rq * 4 + 2];                                              \
      v.w = acc[db][rq * 4 + 3];                                              \
      mO[SLOT][db * 4 + rq][l] = v;                                           \
    }                                                                         \
    mML[SLOT][0][l] = mrow;                                                   \
    mML[SLOT][1][l] = lrow;                                                   \
  } while (0)

#define MERGE(SLOT)                                                           \
  do {                                                                        \
    float m1 = mML[SLOT][0][l], l1 = mML[SLOT][1][l];                         \
    float mnew = fmaxf(mrow, m1);                                             \
    float f0 = exp2f(mrow - mnew);                                            \
    float f1 = exp2f(m1 - mnew);                                              \
    mrow = mnew;                                                              \
    lrow = lrow * f0 + l1 * f1;                                               \
    _Pragma("unroll") for (int db = 0; db < 4; ++db)                          \
    _Pragma("unroll") for (int rq = 0; rq < 4; ++rq) {                        \
      float4 o1 = mO[SLOT][db * 4 + rq][l];                                   \
      acc[db][rq * 4 + 0] = acc[db][rq * 4 + 0] * f0 + o1.x * f1;             \
      acc[db][rq * 4 + 1] = acc[db][rq * 4 + 1] * f0 + o1.y * f1;             \
      acc[db][rq * 4 + 2] = acc[db][rq * 4 + 2] * f0 + o1.z * f1;             \
      acc[db][rq * 4 + 3] = acc[db][rq * 4 + 3] * f0 + o1.w * f1;             \
    }                                                                         \
  } while (0)

  for (int phase = 0; phase < 2; ++phase) {
    const int t = phase ? (63 - x) : x;
    const int q0 = t * 32;

    bf16x8 qf[8];
    {
      const u16* qb = Q + ((size_t)(b * 2048 + q0 + ql)) * 2048 + h * 128 + hi * 8;
#pragma unroll
      for (int ck = 0; ck < 8; ++ck) qf[ck] = *(const bf16x8*)(qb + ck * 16);
    }

    f32x16 acc[4] = {};
    float mrow = -1e30f, lrow = 0.f;

    bf16x8 kfa[8], kfb[8];
    bf16x8 vt[2][4];

    int kv0 = w * 32;
    if (kv0 <= q0) {
      LOADK(kfa, kv0);
      while (true) {
        LOADV(vt, kv0);                       // V(cur) first (issue order)
        bool more = kv0 + 128 <= q0;
        if (more) LOADK(kfb, kv0 + 128);      // K(next) after V(cur)
        COMPUTE(kfa, vt, kv0);
        if (!more) break;
        kv0 += 128;
        LOADV(vt, kv0);
        more = kv0 + 128 <= q0;
        if (more) LOADK(kfa, kv0 + 128);
        COMPUTE(kfb, vt, kv0);
        if (!more) break;
        kv0 += 128;
      }
    }

    if (w >= 2) PUBLISH(w - 2);
    __syncthreads();
    if (w < 2) MERGE(w);
    __syncthreads();
    if (w == 1) PUBLISH(0);
    __syncthreads();
    if (w == 0) {
      MERGE(0);
      float inv = 1.0f / lrow;
      u16* ob = AO + (size_t)(b * 2048 + q0 + ql) * 2048 + h * 128 + hi * 4;
#pragma unroll
      for (int db = 0; db < 4; ++db)
#pragma unroll
        for (int rq = 0; rq < 4; ++rq) {
          ushort4 o;
          o.x = f2b(acc[db][rq * 4 + 0] * inv);
          o.y = f2b(acc[db][rq * 4 + 1] * inv);
          o.z = f2b(acc[db][rq * 4 + 2] * inv);
          o.w = f2b(acc[db][rq * 4 + 3] * inv);
          *(ushort4*)(ob + db * 32 + rq * 8) = o;
        }
    }
    __syncthreads();  // slot reuse guard before next phase's PUBLISH
  }
#undef LOADK
#undef LOADV
#undef COMPUTE
#undef PUBLISH
#undef MERGE
}

// ---------------- host ----------------
extern "C" void kernel_launch(void* const* d_in, const int* in_sizes, int n_in,
                              void* d_out, int out_size, void* d_ws, size_t ws_size,
                              hipStream_t stream) {
  const float* X = (const float*)d_in[0];
  const float* Wq = (const float*)d_in[1];
  const float* Wk = (const float*)d_in[2];
  const float* Wv = (const float*)d_in[3];
  const float* Wo = (const float*)d_in[4];

  u16* ws = (u16*)d_ws;
  const size_t nX = 8388608;   // 2*2048*2048
  const size_t nWq = 4194304;  // 2048*2048
  const size_t nWk = 1048576;  // 512*2048
  u16* Xb = ws;
  u16* Wqb = Xb + nX;          // [Wq|Wk|Wv] contiguous = fused 3072x2048 weight
  u16* Wkb = Wqb + nWq;
  u16* Wvb = Wkb + nWk;
  u16* Wob = Wvb + nWk;
  u16* Qb = Wob + nWq;
  u16* Kfb = Qb + nX;          // K in fragment order (2M u16)
  u16* Vfb = Kfb + 2097152;    // V in fragment order (2M u16)
  u16* AOb = Vfb + 2097152;
  if (ws_size < (size_t)(39845888) * 2) return;

  // fused fp32->bf16: X + Wq + Wk + Wv (Wo converted by gemm256's 64 aux blocks)
  cvt_all<<<2048, 256, 0, stream>>>(X, Wq, Wk, Wv, Xb);

  // fused QKV projection (256^2 8-phase) + Wo conversion on spare blocks
  gemm256<3><<<dim3(16, 16), 512, 0, stream>>>(Xb, Wqb, Qb, 4096, 3072, 2048, Kfb, Vfb,
                                               Wo, Wob);

  attn_fwd<<<dim3(1024), 256, 0, stream>>>(Qb, Kfb, Vfb, AOb);

  // output projection (256x128 8-phase, 256 blocks = full chip) -> fp32 d_out
  gemm_op<<<dim3(16, 16), 512, 0, stream>>>(AOb, Wob, (float*)d_out, 2048);
}